// Round 14
// baseline (657.122 us; speedup 1.0000x reference)
//
#include <hip/hip_runtime.h>
#include <hip/hip_bf16.h>

#define N_NODES 4096
#define E_EDGES 65536
#define IN_F    512
#define H_F     256
#define QD      256
#define NHEAD   8
#define HD      32
#define OUT_F   10
#define L_LAYERS 2
#define CT_N    50

enum { FLAG_RELU = 1, FLAG_ACCUM = 2, FLAG_WF32 = 4, FLAG_WB16 = 8 };

typedef __attribute__((ext_vector_type(8))) __bf16 bf16x8;
typedef __attribute__((ext_vector_type(4))) float f32x4;

union PU { bf16x8 v; __hip_bfloat16 h[8]; __hip_bfloat162 b2[4]; };

// ---------------------------------------------------------------------------
// bf16 MFMA GEMM.  A: bf16 [M][K] row-major (lda).  B: bf16 [N][K] (B^T layout).
// EDGE mode: A-row i built on the fly: relu(Z[tgtp[i]][k] + Z[srcp[i]][256+k] + kbias[k])
// ---------------------------------------------------------------------------
template<int BM, int BN, bool EDGE>
__global__ __launch_bounds__(256) void gemm_mfma(
    const __hip_bfloat16* __restrict__ A, int lda,
    const __hip_bfloat16* __restrict__ B, int ldb,
    float* __restrict__ Cf, __hip_bfloat16* __restrict__ Cb, int ldc,
    int K,
    const float* __restrict__ bias, const float* __restrict__ rowscale,
    const int* __restrict__ tgtp, const int* __restrict__ srcp,
    const float* __restrict__ kbias,
    int flags)
{
    constexpr int WM = BM / 2, WN = BN / 2, MT = WM / 16, NT = WN / 16;
    constexpr int LDT = 40;   // 80B row stride -> max 2-way bank alias (free, m136)
    __shared__ alignas(16) __hip_bfloat16 As[BM * LDT];
    __shared__ alignas(16) __hip_bfloat16 Bs[BN * LDT];

    const int tid = threadIdx.x;
    const int w = tid >> 6, lane = tid & 63, l16 = lane & 15, quad = lane >> 4;
    const int wm = w >> 1, wn = w & 1;
    const int bm = blockIdx.y * BM, bn = blockIdx.x * BN;

    f32x4 acc[MT][NT];
    #pragma unroll
    for (int i = 0; i < MT; ++i)
        #pragma unroll
        for (int j = 0; j < NT; ++j)
            #pragma unroll
            for (int r = 0; r < 4; ++r) acc[i][j][r] = 0.f;

    for (int k0 = 0; k0 < K; k0 += 32) {
        #pragma unroll
        for (int f = tid; f < BM * 4; f += 256) {
            int r = f >> 2, sg = f & 3;
            if (EDGE) {
                int i = bm + r;
                int tg = tgtp[i], sr = srcp[i];
                PU z1, z2, o;
                z1.v = *reinterpret_cast<const bf16x8*>(A + (size_t)tg * 512 + k0 + sg * 8);
                z2.v = *reinterpret_cast<const bf16x8*>(A + (size_t)sr * 512 + 256 + k0 + sg * 8);
                float4 b0 = *reinterpret_cast<const float4*>(kbias + k0 + sg * 8);
                float4 b1 = *reinterpret_cast<const float4*>(kbias + k0 + sg * 8 + 4);
                float bb[8] = {b0.x, b0.y, b0.z, b0.w, b1.x, b1.y, b1.z, b1.w};
                #pragma unroll
                for (int j = 0; j < 8; ++j) {
                    float v = __bfloat162float(z1.h[j]) + __bfloat162float(z2.h[j]) + bb[j];
                    o.h[j] = __float2bfloat16(fmaxf(v, 0.f));
                }
                *reinterpret_cast<bf16x8*>(&As[r * LDT + sg * 8]) = o.v;
            } else {
                *reinterpret_cast<uint4*>(&As[r * LDT + sg * 8]) =
                    *reinterpret_cast<const uint4*>(A + (size_t)(bm + r) * lda + k0 + sg * 8);
            }
        }
        #pragma unroll
        for (int f = tid; f < BN * 4; f += 256) {
            int r = f >> 2, sg = f & 3;
            *reinterpret_cast<uint4*>(&Bs[r * LDT + sg * 8]) =
                *reinterpret_cast<const uint4*>(B + (size_t)(bn + r) * ldb + k0 + sg * 8);
        }
        __syncthreads();
        bf16x8 af[MT], bfr[NT];
        #pragma unroll
        for (int mt = 0; mt < MT; ++mt)
            af[mt] = *reinterpret_cast<const bf16x8*>(&As[(wm * WM + mt * 16 + l16) * LDT + quad * 8]);
        #pragma unroll
        for (int nt = 0; nt < NT; ++nt)
            bfr[nt] = *reinterpret_cast<const bf16x8*>(&Bs[(wn * WN + nt * 16 + l16) * LDT + quad * 8]);
        #pragma unroll
        for (int mt = 0; mt < MT; ++mt)
            #pragma unroll
            for (int nt = 0; nt < NT; ++nt)
                acc[mt][nt] = __builtin_amdgcn_mfma_f32_16x16x32_bf16(af[mt], bfr[nt], acc[mt][nt], 0, 0, 0);
        __syncthreads();
    }

    #pragma unroll
    for (int mt = 0; mt < MT; ++mt) {
        #pragma unroll
        for (int nt = 0; nt < NT; ++nt) {
            int col = bn + wn * WN + nt * 16 + l16;
            #pragma unroll
            for (int r = 0; r < 4; ++r) {
                int row = bm + wm * WM + mt * 16 + quad * 4 + r;
                float v = acc[mt][nt][r];
                if (bias) {
                    float bv = bias[col];
                    if (rowscale) bv *= rowscale[row];
                    v += bv;
                }
                if (flags & FLAG_RELU) v = fmaxf(v, 0.f);
                size_t off = (size_t)row * ldc + col;
                if (flags & FLAG_ACCUM)     Cf[off] += v;
                else if (flags & FLAG_WF32) Cf[off] = v;
                if (flags & FLAG_WB16)      Cb[off] = __float2bfloat16(v);
            }
        }
    }
}

// ---------------------------------------------------------------------------
// Per-slice output descriptor (shared by gemm_fat epilogue and gemm_bz).
// ---------------------------------------------------------------------------
struct GSet { const __hip_bfloat16* A; int lda; const __hip_bfloat16* B;
              const float* bias; const float* rowscale;
              const float* extra; float esc; float cscale;
              __hip_bfloat16* C; float* Cf; int vtout; int ldc; int coloff; };
struct GPack { GSet s[8]; };

// ---------------------------------------------------------------------------
// Fat projection GEMM: C_all = h16[4096][256] @ WCat^T (WCat: [2048][256]),
// one 128x128-tile launch covering all 8 projection slices; per-column-slice
// epilogue (slice = col>>8): bias / ce-gather / cscale / vtout / Z12 packing.
// 16 MFMA per LDS round-trip per wave (vs 4 in the 64x64 kernel).
// ---------------------------------------------------------------------------
__global__ __launch_bounds__(256) void gemm_fat(
    const __hip_bfloat16* __restrict__ A,
    const __hip_bfloat16* __restrict__ B,
    GPack p, const int* __restrict__ eidx)
{
    constexpr int LDT = 40;
    __shared__ alignas(16) __hip_bfloat16 As[128 * LDT];
    __shared__ alignas(16) __hip_bfloat16 Bs[128 * LDT];

    const int tid = threadIdx.x;
    const int w = tid >> 6, lane = tid & 63, l16 = lane & 15, quad = lane >> 4;
    const int wm = w >> 1, wn = w & 1;
    const int bm = blockIdx.y * 128, bn = blockIdx.x * 128;

    f32x4 acc[4][4];
    #pragma unroll
    for (int i = 0; i < 4; ++i)
        #pragma unroll
        for (int j = 0; j < 4; ++j)
            #pragma unroll
            for (int r = 0; r < 4; ++r) acc[i][j][r] = 0.f;

    for (int k0 = 0; k0 < 256; k0 += 32) {
        #pragma unroll
        for (int f = tid; f < 512; f += 256) {
            int r = f >> 2, sg = f & 3;
            *reinterpret_cast<uint4*>(&As[r * LDT + sg * 8]) =
                *reinterpret_cast<const uint4*>(A + (size_t)(bm + r) * 256 + k0 + sg * 8);
            *reinterpret_cast<uint4*>(&Bs[r * LDT + sg * 8]) =
                *reinterpret_cast<const uint4*>(B + (size_t)(bn + r) * 256 + k0 + sg * 8);
        }
        __syncthreads();
        bf16x8 af[4], bfr[4];
        #pragma unroll
        for (int mt = 0; mt < 4; ++mt)
            af[mt] = *reinterpret_cast<const bf16x8*>(&As[(wm * 64 + mt * 16 + l16) * LDT + quad * 8]);
        #pragma unroll
        for (int nt = 0; nt < 4; ++nt)
            bfr[nt] = *reinterpret_cast<const bf16x8*>(&Bs[(wn * 64 + nt * 16 + l16) * LDT + quad * 8]);
        #pragma unroll
        for (int mt = 0; mt < 4; ++mt)
            #pragma unroll
            for (int nt = 0; nt < 4; ++nt)
                acc[mt][nt] = __builtin_amdgcn_mfma_f32_16x16x32_bf16(af[mt], bfr[nt], acc[mt][nt], 0, 0, 0);
        __syncthreads();
    }

    #pragma unroll
    for (int nt = 0; nt < 4; ++nt) {
        int colG = bn + wn * 64 + nt * 16 + l16;
        GSet g = p.s[colG >> 8];
        int col = colG & 255;
        #pragma unroll
        for (int mt = 0; mt < 4; ++mt) {
            #pragma unroll
            for (int r = 0; r < 4; ++r) {
                int row = bm + wm * 64 + mt * 16 + quad * 4 + r;
                float v = acc[mt][nt][r];
                if (g.bias)  v += g.bias[col];
                if (g.extra) v += g.esc * g.extra[(size_t)eidx[row] * QD + col];
                v *= g.cscale;
                if (g.vtout)
                    g.C[(size_t)col * 4096 + row] = __float2bfloat16(v);
                else
                    g.C[(size_t)row * g.ldc + g.coloff + col] = __float2bfloat16(v);
            }
        }
    }
}

// ---------------------------------------------------------------------------
// Batched (grid.z) 64x64 GEMM slices (kept for the two fp32-output GEMMs with
// different A matrices): M=4096, N=256, K=256.
// ---------------------------------------------------------------------------
__global__ __launch_bounds__(256) void gemm_bz(GPack p, const int* __restrict__ eidx)
{
    GSet g = p.s[blockIdx.z];
    constexpr int LDT = 40;
    __shared__ alignas(16) __hip_bfloat16 As[64 * LDT];
    __shared__ alignas(16) __hip_bfloat16 Bs[64 * LDT];

    const int tid = threadIdx.x;
    const int w = tid >> 6, lane = tid & 63, l16 = lane & 15, quad = lane >> 4;
    const int wm = w >> 1, wn = w & 1;
    const int bm = blockIdx.y * 64, bn = blockIdx.x * 64;

    f32x4 acc[2][2];
    #pragma unroll
    for (int i = 0; i < 2; ++i)
        #pragma unroll
        for (int j = 0; j < 2; ++j)
            #pragma unroll
            for (int r = 0; r < 4; ++r) acc[i][j][r] = 0.f;

    for (int k0 = 0; k0 < 256; k0 += 32) {
        #pragma unroll
        for (int f = tid; f < 256; f += 256) {
            int r = f >> 2, sg = f & 3;
            *reinterpret_cast<uint4*>(&As[r * LDT + sg * 8]) =
                *reinterpret_cast<const uint4*>(g.A + (size_t)(bm + r) * g.lda + k0 + sg * 8);
            *reinterpret_cast<uint4*>(&Bs[r * LDT + sg * 8]) =
                *reinterpret_cast<const uint4*>(g.B + (size_t)(bn + r) * 256 + k0 + sg * 8);
        }
        __syncthreads();
        bf16x8 af[2], bfr[2];
        #pragma unroll
        for (int mt = 0; mt < 2; ++mt)
            af[mt] = *reinterpret_cast<const bf16x8*>(&As[(wm * 32 + mt * 16 + l16) * LDT + quad * 8]);
        #pragma unroll
        for (int nt = 0; nt < 2; ++nt)
            bfr[nt] = *reinterpret_cast<const bf16x8*>(&Bs[(wn * 32 + nt * 16 + l16) * LDT + quad * 8]);
        #pragma unroll
        for (int mt = 0; mt < 2; ++mt)
            #pragma unroll
            for (int nt = 0; nt < 2; ++nt)
                acc[mt][nt] = __builtin_amdgcn_mfma_f32_16x16x32_bf16(af[mt], bfr[nt], acc[mt][nt], 0, 0, 0);
        __syncthreads();
    }

    #pragma unroll
    for (int mt = 0; mt < 2; ++mt) {
        #pragma unroll
        for (int nt = 0; nt < 2; ++nt) {
            int colL = bn + wn * 32 + nt * 16 + l16;
            #pragma unroll
            for (int r = 0; r < 4; ++r) {
                int row = bm + wm * 32 + mt * 16 + quad * 4 + r;
                float v = acc[mt][nt][r];
                if (g.bias) {
                    float bv = g.bias[colL];
                    if (g.rowscale) bv *= g.rowscale[row];
                    v += bv;
                }
                if (g.extra) v += g.esc * g.extra[(size_t)eidx[row] * QD + colL];
                v *= g.cscale;
                if (g.vtout)
                    g.C[(size_t)colL * 4096 + row] = __float2bfloat16(v);
                else if (g.Cf)
                    g.Cf[(size_t)row * g.ldc + g.coloff + colL] = v;
                else
                    g.C[(size_t)row * g.ldc + g.coloff + colL] = __float2bfloat16(v);
            }
        }
    }
}

// ---------------------------------------------------------------------------
// fp32 tiled composite-weight GEMM (startup): 32x32 tile, BK=16, 2x2 microtile.
// ---------------------------------------------------------------------------
struct FDesc { const float* A; int lda; const float* B; int ldb; int tb;
               const float* bias; float* C; int M, N, K; };
struct FPack { FDesc d[16]; };

__global__ __launch_bounds__(256) void fgemm2(FPack p)
{
    FDesc c = p.d[blockIdx.z];
    int bm = blockIdx.y * 32, bn = blockIdx.x * 32;
    if (bm >= c.M || bn >= c.N) return;
    __shared__ float As[16][33];
    __shared__ float Bs[16][33];
    int tid = threadIdx.x;
    int tr = tid / 16, tc = tid % 16;
    float acc[2][2] = {};

    for (int k0 = 0; k0 < c.K; k0 += 16) {
        #pragma unroll
        for (int u = 0; u < 2; ++u) {
            int i = tid * 2 + u;
            int m = i >> 4, kk = i & 15;
            int row = bm + m, kg = k0 + kk;
            As[kk][m] = (row < c.M && kg < c.K) ? c.A[(size_t)row * c.lda + kg] : 0.f;
        }
        if (c.tb) {
            #pragma unroll
            for (int u = 0; u < 2; ++u) {
                int i = tid * 2 + u;
                int n = i >> 4, kk = i & 15;
                int col = bn + n, kg = k0 + kk;
                Bs[kk][n] = (col < c.N && kg < c.K) ? c.B[(size_t)col * c.ldb + kg] : 0.f;
            }
        } else {
            #pragma unroll
            for (int u = 0; u < 2; ++u) {
                int i = tid * 2 + u;
                int kk = i >> 5, n = i & 31;
                int col = bn + n, kg = k0 + kk;
                Bs[kk][n] = (col < c.N && kg < c.K) ? c.B[(size_t)kg * c.ldb + col] : 0.f;
            }
        }
        __syncthreads();
        #pragma unroll
        for (int kk = 0; kk < 16; ++kk) {
            float a0 = As[kk][tr * 2], a1 = As[kk][tr * 2 + 1];
            float b0 = Bs[kk][tc * 2], b1 = Bs[kk][tc * 2 + 1];
            acc[0][0] = fmaf(a0, b0, acc[0][0]);
            acc[0][1] = fmaf(a0, b1, acc[0][1]);
            acc[1][0] = fmaf(a1, b0, acc[1][0]);
            acc[1][1] = fmaf(a1, b1, acc[1][1]);
        }
        __syncthreads();
    }

    #pragma unroll
    for (int i = 0; i < 2; ++i) {
        int row = bm + tr * 2 + i;
        if (row >= c.M) continue;
        #pragma unroll
        for (int j = 0; j < 2; ++j) {
            int col = bn + tc * 2 + j;
            if (col >= c.N) continue;
            float v = acc[i][j];
            if (c.bias) v += c.bias[col];
            c.C[(size_t)row * c.N + col] = v;
        }
    }
}

// ---------------------------------------------------------------------------
// Flash MHA v9: max-free exp2 softmax, 32 q-rows shared by 8 waves (512-thr
// blocks, 8-way key split), additive merge.  grid (128, 8).
// ---------------------------------------------------------------------------
__global__ __launch_bounds__(512) void mha_flash9(
    const __hip_bfloat16* __restrict__ Qm,
    const __hip_bfloat16* __restrict__ Km,
    const __hip_bfloat16* __restrict__ Vt, __hip_bfloat16* __restrict__ Out)
{
    const int hh = blockIdx.y;
    const int tid = threadIdx.x;
    const int w = tid >> 6, lane = tid & 63, l16 = lane & 15, quad = lane >> 4;
    const int qb = blockIdx.x * 32;

    __shared__ float Osh[7][2][64][8];
    __shared__ float Lsh[7][2][16];

    const bf16x8 aq0 = *reinterpret_cast<const bf16x8*>(
        Qm + (size_t)(qb + l16) * 256 + hh * 32 + quad * 8);
    const bf16x8 aq1 = *reinterpret_cast<const bf16x8*>(
        Qm + (size_t)(qb + 16 + l16) * 256 + hh * 32 + quad * 8);
    const __hip_bfloat16* vb0 = Vt + (size_t)(hh * 32 + l16) * 4096;
    const __hip_bfloat16* vb1 = vb0 + (size_t)16 * 4096;
    const int rowoff = (l16 >> 2) * 8 + (l16 & 3);
    const f32x4 zero = {0.f, 0.f, 0.f, 0.f};

    f32x4 o00 = zero, o01 = zero, o10 = zero, o11 = zero;
    float l0 = 0.f, l1 = 0.f;

    const int kstart = w * 512;
    for (int kt = 0; kt < 8; ++kt) {
        const int kbase = kstart + kt * 64;
        bf16x8 kf[4];
        #pragma unroll
        for (int c = 0; c < 2; ++c)
            #pragma unroll
            for (int st = 0; st < 2; ++st)
                kf[c * 2 + st] = *reinterpret_cast<const bf16x8*>(
                    Km + (size_t)(kbase + c * 32 + st * 4 + rowoff) * 256 + hh * 32 + quad * 8);
        bf16x8 v00 = *reinterpret_cast<const bf16x8*>(vb0 + kbase + quad * 8);
        bf16x8 v01 = *reinterpret_cast<const bf16x8*>(vb1 + kbase + quad * 8);
        bf16x8 v10 = *reinterpret_cast<const bf16x8*>(vb0 + kbase + 32 + quad * 8);
        bf16x8 v11 = *reinterpret_cast<const bf16x8*>(vb1 + kbase + 32 + quad * 8);

        // ---- set 0 ----
        {
            f32x4 s[4];
            #pragma unroll
            for (int i = 0; i < 4; ++i)
                s[i] = __builtin_amdgcn_mfma_f32_16x16x32_bf16(kf[i], aq0, zero, 0, 0, 0);
            PU p0, p1;
            float ls = 0.f;
            #pragma unroll
            for (int i = 0; i < 4; ++i) {
                float e0 = exp2f(s[i][0]), e1 = exp2f(s[i][1]);
                float e2 = exp2f(s[i][2]), e3 = exp2f(s[i][3]);
                ls += (e0 + e1) + (e2 + e3);
                PU& pp = (i < 2) ? p0 : p1;
                pp.b2[(i & 1) * 2 + 0] = __float22bfloat162_rn(make_float2(e0, e1));
                pp.b2[(i & 1) * 2 + 1] = __float22bfloat162_rn(make_float2(e2, e3));
            }
            l0 += ls;
            o00 = __builtin_amdgcn_mfma_f32_16x16x32_bf16(v00, p0.v, o00, 0, 0, 0);
            o01 = __builtin_amdgcn_mfma_f32_16x16x32_bf16(v01, p0.v, o01, 0, 0, 0);
            o00 = __builtin_amdgcn_mfma_f32_16x16x32_bf16(v10, p1.v, o00, 0, 0, 0);
            o01 = __builtin_amdgcn_mfma_f32_16x16x32_bf16(v11, p1.v, o01, 0, 0, 0);
        }
        // ---- set 1 ----
        {
            f32x4 s[4];
            #pragma unroll
            for (int i = 0; i < 4; ++i)
                s[i] = __builtin_amdgcn_mfma_f32_16x16x32_bf16(kf[i], aq1, zero, 0, 0, 0);
            PU p0, p1;
            float ls = 0.f;
            #pragma unroll
            for (int i = 0; i < 4; ++i) {
                float e0 = exp2f(s[i][0]), e1 = exp2f(s[i][1]);
                float e2 = exp2f(s[i][2]), e3 = exp2f(s[i][3]);
                ls += (e0 + e1) + (e2 + e3);
                PU& pp = (i < 2) ? p0 : p1;
                pp.b2[(i & 1) * 2 + 0] = __float22bfloat162_rn(make_float2(e0, e1));
                pp.b2[(i & 1) * 2 + 1] = __float22bfloat162_rn(make_float2(e2, e3));
            }
            l1 += ls;
            o10 = __builtin_amdgcn_mfma_f32_16x16x32_bf16(v00, p0.v, o10, 0, 0, 0);
            o11 = __builtin_amdgcn_mfma_f32_16x16x32_bf16(v01, p0.v, o11, 0, 0, 0);
            o10 = __builtin_amdgcn_mfma_f32_16x16x32_bf16(v10, p1.v, o10, 0, 0, 0);
            o11 = __builtin_amdgcn_mfma_f32_16x16x32_bf16(v11, p1.v, o11, 0, 0, 0);
        }
    }

    l0 += __shfl_xor(l0, 16); l0 += __shfl_xor(l0, 32);
    l1 += __shfl_xor(l1, 16); l1 += __shfl_xor(l1, 32);

    if (w > 0) {
        #pragma unroll
        for (int r = 0; r < 4; ++r) {
            Osh[w - 1][0][lane][r]     = o00[r];
            Osh[w - 1][0][lane][4 + r] = o01[r];
            Osh[w - 1][1][lane][r]     = o10[r];
            Osh[w - 1][1][lane][4 + r] = o11[r];
        }
        if (quad == 0) { Lsh[w - 1][0][l16] = l0; Lsh[w - 1][1][l16] = l1; }
    }
    __syncthreads();
    if (w == 0) {
        #pragma unroll
        for (int ww = 0; ww < 7; ++ww) {
            #pragma unroll
            for (int r = 0; r < 4; ++r) {
                o00[r] += Osh[ww][0][lane][r];
                o01[r] += Osh[ww][0][lane][4 + r];
                o10[r] += Osh[ww][1][lane][r];
                o11[r] += Osh[ww][1][lane][4 + r];
            }
            l0 += Lsh[ww][0][l16];
            l1 += Lsh[ww][1][l16];
        }
        {
            float inv = 1.f / l0;
            __hip_bfloat16* dst = Out + (size_t)(qb + l16) * 256 + hh * 32;
            #pragma unroll
            for (int r = 0; r < 4; ++r) {
                dst[quad * 4 + r]      = __float2bfloat16(o00[r] * inv);
                dst[16 + quad * 4 + r] = __float2bfloat16(o01[r] * inv);
            }
        }
        {
            float inv = 1.f / l1;
            __hip_bfloat16* dst = Out + (size_t)(qb + 16 + l16) * 256 + hh * 32;
            #pragma unroll
            for (int r = 0; r < 4; ++r) {
                dst[quad * 4 + r]      = __float2bfloat16(o10[r] * inv);
                dst[16 + quad * 4 + r] = __float2bfloat16(o11[r] * inv);
            }
        }
    }
}

// build mask bitfield + per-target degree count in one pass
__global__ __launch_bounds__(256) void build_mask(const int* __restrict__ src,
                                                  const int* __restrict__ tgt,
                                                  unsigned* __restrict__ mb,
                                                  int* __restrict__ cnt)
{
    int e = blockIdx.x * 256 + threadIdx.x;
    if (e >= E_EDGES) return;
    int t = tgt[e];
    atomicOr(mb + (size_t)src[e] * (N_NODES / 32) + (t >> 5), 1u << (t & 31));
    atomicAdd(&cnt[t], 1);
}

__global__ __launch_bounds__(1024) void csr_scan(const int* __restrict__ cnt, int* __restrict__ off,
                                                 int* __restrict__ cursor, float* __restrict__ degf)
{
    __shared__ int sh[1024];
    int t = threadIdx.x;
    int base = t * 4;
    int c0 = cnt[base], c1 = cnt[base + 1], c2 = cnt[base + 2], c3 = cnt[base + 3];
    int sum = c0 + c1 + c2 + c3;
    sh[t] = sum; __syncthreads();
    for (int d = 1; d < 1024; d <<= 1) {
        int v = (t >= d) ? sh[t - d] : 0;
        __syncthreads();
        sh[t] += v;
        __syncthreads();
    }
    int excl = sh[t] - sum;
    int o0 = excl, o1 = excl + c0, o2 = o1 + c1, o3 = o2 + c2;
    off[base] = o0; off[base + 1] = o1; off[base + 2] = o2; off[base + 3] = o3;
    cursor[base] = o0; cursor[base + 1] = o1; cursor[base + 2] = o2; cursor[base + 3] = o3;
    degf[base] = (float)c0; degf[base + 1] = (float)c1;
    degf[base + 2] = (float)c2; degf[base + 3] = (float)c3;
    if (t == 1023) off[4096] = sh[t];
}

__global__ __launch_bounds__(256) void csr_fill(const int* __restrict__ src, const int* __restrict__ tgt,
                                                int* __restrict__ cursor,
                                                int* __restrict__ srcp, int* __restrict__ tgtp)
{
    int e = blockIdx.x * 256 + threadIdx.x;
    if (e >= E_EDGES) return;
    int t = tgt[e];
    int pos = atomicAdd(&cursor[t], 1);
    srcp[pos] = src[e];
    tgtp[pos] = t;
}

__global__ __launch_bounds__(256) void seg_sum(const int* __restrict__ off,
                                               const __hip_bfloat16* __restrict__ M2,
                                               __hip_bfloat16* __restrict__ A3)
{
    int n = blockIdx.x, t = threadIdx.x;
    int b0 = off[n], b1 = off[n + 1];
    float s = 0.f;
    for (int i = b0; i < b1; ++i)
        s += __bfloat162float(M2[(size_t)i * 256 + t]);
    A3[(size_t)n * 256 + t] = __float2bfloat16(s);
}

// Sparse graph-masked attention over bf16 Q,K,V. Writes out (=).
__global__ __launch_bounds__(256) void sparse_attn(
    const __hip_bfloat16* __restrict__ Q, const __hip_bfloat16* __restrict__ K,
    const __hip_bfloat16* __restrict__ V, int vld,
    const unsigned* __restrict__ maskb, float* __restrict__ outb)
{
    int i = blockIdx.x, t = threadIdx.x;
    __shared__ float qsh[256];
    __shared__ int   nb[1024];
    __shared__ float sc[1024];
    __shared__ int   cnt;
    __shared__ float red[4];
    __shared__ float smax, ssum;
    if (t == 0) cnt = 0;
    qsh[t] = __bfloat162float(Q[(size_t)i * 256 + t]);
    __syncthreads();
    if (t < 128) {
        unsigned wv = maskb[(size_t)i * 128 + t];
        while (wv) {
            int b = __ffs(wv) - 1; wv &= wv - 1;
            int p = atomicAdd(&cnt, 1);
            nb[p] = t * 32 + b;
        }
    }
    __syncthreads();
    int deg = cnt;
    int wid = t >> 6, lane = t & 63;
    if (deg > 0) {
        for (int n = wid; n < deg; n += 4) {
            union { uint2 u; __hip_bfloat16 h[4]; } kv;
            kv.u = *reinterpret_cast<const uint2*>(K + (size_t)nb[n] * 256 + lane * 4);
            float s = qsh[lane*4+0] * __bfloat162float(kv.h[0]) + qsh[lane*4+1] * __bfloat162float(kv.h[1])
                    + qsh[lane*4+2] * __bfloat162float(kv.h[2]) + qsh[lane*4+3] * __bfloat162float(kv.h[3]);
            #pragma unroll
            for (int off = 32; off; off >>= 1) s += __shfl_xor(s, off);
            if (lane == 0) sc[n] = s * 0.0625f;
        }
        __syncthreads();
        float m = -3.4e38f;
        for (int n = t; n < deg; n += 256) m = fmaxf(m, sc[n]);
        #pragma unroll
        for (int off = 32; off; off >>= 1) m = fmaxf(m, __shfl_xor(m, off));
        if (lane == 0) red[wid] = m;
        __syncthreads();
        if (t == 0) smax = fmaxf(fmaxf(red[0], red[1]), fmaxf(red[2], red[3]));
        __syncthreads();
        float ls = 0.f;
        for (int n = t; n < deg; n += 256) { float e = __expf(sc[n] - smax); sc[n] = e; ls += e; }
        #pragma unroll
        for (int off = 32; off; off >>= 1) ls += __shfl_xor(ls, off);
        if (lane == 0) red[wid] = ls;
        __syncthreads();
        if (t == 0) ssum = red[0] + red[1] + red[2] + red[3];
        __syncthreads();
        float inv = 1.f / ssum;
        float o = 0.f;
        for (int n = 0; n < deg; ++n)
            o += sc[n] * __bfloat162float(V[(size_t)nb[n] * vld + t]);
        outb[(size_t)i * 256 + t] = o * inv;
    } else {
        float o = 0.f;
        for (int j = 0; j < N_NODES; ++j) o += __bfloat162float(V[(size_t)j * vld + t]);
        outb[(size_t)i * 256 + t] = o * (1.f / N_NODES);
    }
}

// h = LN(h + a1 + a2 + a3)
__global__ __launch_bounds__(256) void ln_kernel(float* __restrict__ h, __hip_bfloat16* __restrict__ h16,
                                                 const float* __restrict__ a1,
                                                 const float* __restrict__ a2,
                                                 const float* __restrict__ a3,
                                                 const float* __restrict__ g, const float* __restrict__ b)
{
    int row = blockIdx.x, t = threadIdx.x;
    __shared__ float red[256];
    size_t off = ((size_t)row << 8) + t;
    float v = h[off] + a1[off] + a2[off] + a3[off];
    red[t] = v; __syncthreads();
    for (int s = 128; s > 0; s >>= 1) { if (t < s) red[t] += red[t + s]; __syncthreads(); }
    float mu = red[0] * (1.f / 256.f); __syncthreads();
    float d = v - mu;
    red[t] = d * d; __syncthreads();
    for (int s = 128; s > 0; s >>= 1) { if (t < s) red[t] += red[t + s]; __syncthreads(); }
    float var = red[0] * (1.f / 256.f);
    float r = d * rsqrtf(var + 1e-5f) * g[t] + b[t];
    h[off] = r;
    h16[off] = __float2bfloat16(r);
}

__global__ __launch_bounds__(256) void colpool(const float* __restrict__ h, float* __restrict__ p)
{
    int c = blockIdx.x, t = threadIdx.x;
    __shared__ float rs[256], rm[256];
    float s = 0.f, m = -3.4e38f;
    for (int row = t; row < N_NODES; row += 256) {
        float v = h[((size_t)row << 8) + c];
        s += v; m = fmaxf(m, v);
    }
    rs[t] = s; rm[t] = m; __syncthreads();
    for (int st = 128; st > 0; st >>= 1) {
        if (t < st) { rs[t] += rs[t + st]; rm[t] = fmaxf(rm[t], rm[t + st]); }
        __syncthreads();
    }
    if (t == 0) { p[c] = rs[0] * (1.f / N_NODES); p[256 + c] = rm[0]; }
}

__global__ __launch_bounds__(256) void classifier(const float* __restrict__ pooled,
                                                  const float* __restrict__ Wc1, const float* __restrict__ bc1,
                                                  const float* __restrict__ Wc2, const float* __restrict__ bc2,
                                                  float* __restrict__ out)
{
    __shared__ float p[512];
    __shared__ float z[256];
    int t = threadIdx.x;
    p[t] = pooled[t]; p[256 + t] = pooled[256 + t];
    __syncthreads();
    float s = bc1[t];
    for (int k = 0; k < 512; ++k) s = fmaf(p[k], Wc1[k * 256 + t], s);
    z[t] = fmaxf(s, 0.f);
    __syncthreads();
    if (t < OUT_F) {
        float o = bc2[t];
        for (int j = 0; j < 256; ++j) o = fmaf(z[j], Wc2[j * OUT_F + t], o);
        out[t] = o;
    }
}

// ---- bf16 conversion ----
struct CDesc { const float* s; __hip_bfloat16* d; int total; };
struct CPack { CDesc d[2]; };
__global__ __launch_bounds__(256) void convert_copy(CPack p)
{
    CDesc c = p.d[blockIdx.y];
    for (int i = blockIdx.x * 256 + threadIdx.x; i < c.total; i += gridDim.x * 256)
        c.d[i] = __float2bfloat16(c.s[i]);
}
// LDS-tiled transpose-convert: d[n*K+k] = bf16(s[k*sld+n]); coalesced both sides
struct TDesc { const float* s; __hip_bfloat16* d; int K, N, sld; };
struct TPack { TDesc d[23]; };
__global__ __launch_bounds__(256) void convert_t32(TPack p)
{
    TDesc c = p.d[blockIdx.z];
    int k0 = blockIdx.x * 32, n0 = blockIdx.y * 32;
    if (k0 >= c.K || n0 >= c.N) return;
    __shared__ float t[32][33];
    int tr = threadIdx.x >> 5, tc = threadIdx.x & 31;
    #pragma unroll
    for (int rr = 0; rr < 32; rr += 8)
        t[tc][tr + rr] = c.s[(size_t)(k0 + tr + rr) * c.sld + n0 + tc];
    __syncthreads();
    #pragma unroll
    for (int rr = 0; rr < 32; rr += 8)
        c.d[(size_t)(n0 + tr + rr) * c.K + k0 + tc] = __float2bfloat16(t[tr + rr][tc]);
}

extern "C" void kernel_launch(void* const* d_in, const int* in_sizes, int n_in,
                              void* d_out, int out_size, void* d_ws, size_t ws_size,
                              hipStream_t stream)
{
    const float* x    = (const float*)d_in[0];
    const int*   ei   = (const int*)d_in[1];
    const int*   ct   = (const int*)d_in[2];
    const float* Wi   = (const float*)d_in[3];
    const float* bi   = (const float*)d_in[4];
    const float* Wq   = (const float*)d_in[5];
    const float* bq   = (const float*)d_in[6];
    const float* Wk   = (const float*)d_in[7];
    const float* bk   = (const float*)d_in[8];
    const float* Wv   = (const float*)d_in[9];
    const float* bv   = (const float*)d_in[10];
    const float* Bc   = (const float*)d_in[11];
    const float* cemb = (const float*)d_in[12];
    const float* Win  = (const float*)d_in[13];
    const float* binp = (const float*)d_in[14];
    const float* Wo   = (const float*)d_in[15];
    const float* bo   = (const float*)d_in[16];
    const float* Wm1  = (const float*)d_in[17];
    const float* bm1  = (const float*)d_in[18];
    const float* Wm2  = (const float*)d_in[19];
    const float* bm2  = (const float*)d_in[20];
    const float* Wm3  = (const float*)d_in[21];
    const float* bm3  = (const float*)d_in[22];
    const float* lng  = (const float*)d_in[23];
    const float* lnb  = (const float*)d_in[24];
    const float* Wc1  = (const float*)d_in[25];
    const float* bc1  = (const float*)d_in[26];
    const float* Wc2  = (const float*)d_in[27];
    const float* bc2  = (const float*)d_in[28];

    const int* src = ei;
    const int* tgt = ei + E_EDGES;

    // ---- workspace carve-up ----
    char* wp = (char*)d_ws;
    auto alloc = [&](size_t bytes) { char* r = wp; wp += (bytes + 255) & ~(size_t)255; return r; };
    const size_t NH = (size_t)N_NODES * 256;
    float* h      = (float*)alloc(NH * 4);
    float* a1     = (float*)alloc(NH * 4);
    float* a2     = (float*)alloc(NH * 4);
    float* a3     = (float*)alloc(NH * 4);
    float* pooled = (float*)alloc(512 * 4);
    float* degf   = (float*)alloc(N_NODES * 4);
    __hip_bfloat16* x16 = (__hip_bfloat16*)alloc((size_t)N_NODES * 512 * 2);
    __hip_bfloat16* h16 = (__hip_bfloat16*)alloc(NH * 2);
    __hip_bfloat16* Qb  = (__hip_bfloat16*)alloc(NH * 2);
    __hip_bfloat16* Kb  = (__hip_bfloat16*)alloc(NH * 2);
    __hip_bfloat16* Vb  = (__hip_bfloat16*)alloc(NH * 2);
    __hip_bfloat16* Tq  = (__hip_bfloat16*)alloc(NH * 2);
    __hip_bfloat16* Tk  = (__hip_bfloat16*)alloc(NH * 2);
    __hip_bfloat16* Vt  = (__hip_bfloat16*)alloc(NH * 2);
    __hip_bfloat16* Z12 = (__hip_bfloat16*)alloc((size_t)N_NODES * 512 * 2);
    __hip_bfloat16* M216= (__hip_bfloat16*)alloc((size_t)E_EDGES * 256 * 2);
    __hip_bfloat16* A3  = (__hip_bfloat16*)alloc(NH * 2);
    __hip_bfloat16* Wi_t= (__hip_bfloat16*)alloc((size_t)256 * 512 * 2);
    // fp32 composite weights / biases / ce-tables, per layer
    float *Wqc_f[2], *Wkc_f[2], *Wqm_f[2], *Wkm_f[2], *Wvm_f[2];
    float *bqc[2], *bkc[2], *bqm[2], *bkm[2], *bvm[2], *ceq2[2], *cek2[2];
    for (int l = 0; l < 2; ++l) {
        Wqc_f[l] = (float*)alloc(65536 * 4); Wkc_f[l] = (float*)alloc(65536 * 4);
        Wqm_f[l] = (float*)alloc(65536 * 4); Wkm_f[l] = (float*)alloc(65536 * 4);
        Wvm_f[l] = (float*)alloc(65536 * 4);
        bqc[l] = (float*)alloc(256 * 4); bkc[l] = (float*)alloc(256 * 4);
        bqm[l] = (float*)alloc(256 * 4); bkm[l] = (float*)alloc(256 * 4);
        bvm[l] = (float*)alloc(256 * 4);
        ceq2[l] = (float*)alloc(CT_N * 256 * 4); cek2[l] = (float*)alloc(CT_N * 256 * 4);
    }
    // bf16 weights: WCat[l] = [2048][256] (8 projection slices), plus Wm2, Wo, Wm3
    __hip_bfloat16* WCat[2];
    __hip_bfloat16* WM2[2];
    __hip_bfloat16* WOo[2];
    __hip_bfloat16* WM3[2];
    for (int l = 0; l < 2; ++l) {
        WCat[l] = (__hip_bfloat16*)alloc((size_t)2048 * 256 * 2);
        WM2[l]  = (__hip_bfloat16*)alloc(65536 * 2);
        WOo[l]  = (__hip_bfloat16*)alloc(65536 * 2);
        WM3[l]  = (__hip_bfloat16*)alloc(65536 * 2);
    }
    unsigned* maskb = (unsigned*)alloc((size_t)N_NODES * 128 * 4);
    int* cnt    = (int*)alloc(N_NODES * 4);
    int* cursor = (int*)alloc(N_NODES * 4);
    int* off    = (int*)alloc((N_NODES + 1) * 4);
    int* srcp   = (int*)alloc(E_EDGES * 4);
    int* tgtp   = (int*)alloc(E_EDGES * 4);

    // ---- startup: x conversion ----
    CPack cp; cp.d[0] = {x, x16, N_NODES * 512};
    convert_copy<<<dim3(256, 1), 256, 0, stream>>>(cp);

    // ---- composite fp32 weights (tiled fgemm2, 2 dependent waves) ----
    FPack f1; int n1 = 0;
    FPack f2; int n2 = 0;
    for (int l = 0; l < 2; ++l) {
        const float* Wq_l  = Wq + (size_t)l * 65536;
        const float* Wk_l  = Wk + (size_t)l * 65536;
        const float* Wv_l  = Wv + (size_t)l * 65536;
        const float* Bc_l  = Bc + (size_t)l * 65536;
        const float* Win_l = Win + (size_t)l * 256 * 768;
        const float* ce_l  = cemb + (size_t)l * CT_N * QD;
        const float* bq_l  = bq + l * 256;
        const float* bk_l  = bk + l * 256;
        const float* bv_l  = bv + l * 256;
        const float* bin_l = binp + l * 768;
        f1.d[n1++] = {Wq_l, 256, Bc_l, 256, 0, nullptr, Wqc_f[l], 256, 256, 256};
        f1.d[n1++] = {Wk_l, 256, Bc_l, 256, 1, nullptr, Wkc_f[l], 256, 256, 256};
        f1.d[n1++] = {bq_l, 256, Bc_l, 256, 0, nullptr, bqc[l], 1, 256, 256};
        f1.d[n1++] = {bk_l, 256, Bc_l, 256, 1, nullptr, bkc[l], 1, 256, 256};
        f2.d[n2++] = {Wqc_f[l], 256, Win_l,       768, 0, nullptr, Wqm_f[l], 256, 256, 256};
        f2.d[n2++] = {Wkc_f[l], 256, Win_l + 256, 768, 0, nullptr, Wkm_f[l], 256, 256, 256};
        f2.d[n2++] = {Wv_l,     256, Win_l + 512, 768, 0, nullptr, Wvm_f[l], 256, 256, 256};
        f2.d[n2++] = {ce_l,     256, Win_l,       768, 0, nullptr, ceq2[l], CT_N, 256, 256};
        f2.d[n2++] = {ce_l,     256, Win_l + 256, 768, 0, nullptr, cek2[l], CT_N, 256, 256};
        f2.d[n2++] = {bqc[l],   256, Win_l,       768, 0, bin_l,       bqm[l], 1, 256, 256};
        f2.d[n2++] = {bkc[l],   256, Win_l + 256, 768, 0, bin_l + 256, bkm[l], 1, 256, 256};
        f2.d[n2++] = {bv_l,     256, Win_l + 512, 768, 0, bin_l + 512, bvm[l], 1, 256, 256};
    }
    fgemm2<<<dim3(8, 8, n1), 256, 0, stream>>>(f1);
    fgemm2<<<dim3(8, 8, n2), 256, 0, stream>>>(f2);

    // ---- transpose-convert all [K][N] fp32 weights to bf16 [N][K] ----
    // WCat slice order: 0=Wqc 1=Wkc 2=Wv 3=Wqm 4=Wkm 5=Wvm 6=Wm1a 7=Wm1b
    TPack tp; int ndt = 0;
    auto addT = [&](const float* s, __hip_bfloat16* d, int K, int N, int sld) { tp.d[ndt++] = {s, d, K, N, sld}; };
    addT(Wi, Wi_t, 512, 256, 256);
    for (int l = 0; l < 2; ++l) {
        const float* Wv_l  = Wv + (size_t)l * 65536;
        const float* Wo_l  = Wo + (size_t)l * 65536;
        const float* Wm1_l = Wm1 + (size_t)l * (2 * H_F + QD) * QD;  // layer stride 768*256!
        const float* Wm2_l = Wm2 + (size_t)l * 65536;
        const float* Wm3_l = Wm3 + (size_t)l * 65536;
        addT(Wqc_f[l], WCat[l],              256, 256, 256);
        addT(Wkc_f[l], WCat[l] + 65536,      256, 256, 256);
        addT(Wv_l,     WCat[l] + 2 * 65536,  256, 256, 256);
        addT(Wqm_f[l], WCat[l] + 3 * 65536,  256, 256, 256);
        addT(Wkm_f[l], WCat[l] + 4 * 65536,  256, 256, 256);
        addT(Wvm_f[l], WCat[l] + 5 * 65536,  256, 256, 256);
        addT(Wm1_l,              WCat[l] + 6 * 65536, 256, 256, 256);
        addT(Wm1_l + 256 * 256,  WCat[l] + 7 * 65536, 256, 256, 256);
        addT(Wm2_l, WM2[l], 256, 256, 256);
        addT(Wo_l,  WOo[l], 256, 256, 256);
        addT(Wm3_l, WM3[l], 256, 256, 256);
    }
    convert_t32<<<dim3(16, 8, ndt), 256, 0, stream>>>(tp);

    hipMemsetAsync(maskb, 0, (size_t)N_NODES * 128 * 4, stream);
    hipMemsetAsync(cnt, 0, N_NODES * 4, stream);
    build_mask<<<E_EDGES / 256, 256, 0, stream>>>(src, tgt, maskb, cnt);
    csr_scan<<<1, 1024, 0, stream>>>(cnt, off, cursor, degf);
    csr_fill<<<E_EDGES / 256, 256, 0, stream>>>(src, tgt, cursor, srcp, tgtp);

    // h = relu(x @ Wi + bi)
    gemm_mfma<64, 64, false><<<dim3(4, 64), 256, 0, stream>>>(
        x16, 512, Wi_t, 512, h, h16, 256, 512,
        bi, nullptr, nullptr, nullptr, nullptr, FLAG_RELU | FLAG_WF32 | FLAG_WB16);

    const float QSCALE = 0.25507693f;   // log2(e)/sqrt(32)

    for (int l = 0; l < L_LAYERS; ++l) {
        const float* ce_l  = cemb + (size_t)l * CT_N * QD;
        const float* bo_l  = bo + l * QD;
        const float* bm1_l = bm1 + l * QD;
        const float* bm2_l = bm2 + l * QD;
        const float* bm3_l = bm3 + l * H_F;
        const float* lng_l = lng + l * H_F;
        const float* lnb_l = lnb + l * H_F;
        const float* bv_l  = bv + l * 256;

        // ---- ONE fat projection GEMM (M=4096, N=2048) for all 8 slices ----
        {
            GPack gp;
            gp.s[0] = {nullptr, 0, nullptr, bqc[l], nullptr, ce_l,    0.1f, 1.0f,   Qb,  nullptr, 0, 256, 0};
            gp.s[1] = {nullptr, 0, nullptr, bkc[l], nullptr, ce_l,    0.1f, 1.0f,   Kb,  nullptr, 0, 256, 0};
            gp.s[2] = {nullptr, 0, nullptr, bv_l,   nullptr, nullptr, 0.f,  1.0f,   Vb,  nullptr, 0, 256, 0};
            gp.s[3] = {nullptr, 0, nullptr, bqm[l], nullptr, ceq2[l], 0.1f, QSCALE, Tq,  nullptr, 0, 256, 0};
            gp.s[4] = {nullptr, 0, nullptr, bkm[l], nullptr, cek2[l], 0.1f, 1.0f,   Tk,  nullptr, 0, 256, 0};
            gp.s[5] = {nullptr, 0, nullptr, bvm[l], nullptr, nullptr, 0.f,  1.0f,   Vt,  nullptr, 1, 256, 0};
            gp.s[6] = {nullptr, 0, nullptr, nullptr, nullptr, nullptr, 0.f, 1.0f,   Z12, nullptr, 0, 512, 0};
            gp.s[7] = {nullptr, 0, nullptr, nullptr, nullptr, nullptr, 0.f, 1.0f,   Z12, nullptr, 0, 512, 256};
            gemm_fat<<<dim3(16, 32), 256, 0, stream>>>(h16, WCat[l], gp, ct);
        }

        // sparse graph-masked attention -> a1
        sparse_attn<<<N_NODES, 256, 0, stream>>>(Qb, Kb, Vb, 256, maskb, a1);

        // flash MHA v9: heads -> Qb
        mha_flash9<<<dim3(128, NHEAD), 512, 0, stream>>>(Tq, Tk, Vt, Qb);

        // edge MLP: fused-gather edge GEMM -> M216, seg-sum -> A3
        gemm_mfma<128, 128, true><<<dim3(2, E_EDGES / 128), 256, 0, stream>>>(
            Z12, 512, WM2[l], 256, nullptr, M216, 256, 256,
            bm2_l, nullptr, tgtp, srcp, bm1_l, FLAG_RELU | FLAG_WB16);
        seg_sum<<<N_NODES, 256, 0, stream>>>(off, M216, A3);

        // batched fp32 outputs: a2 = heads@Wo + bo ; a3 = A3@Wm3 + deg*bm3
        {
            GPack gp;
            gp.s[0] = {Qb, 256, WOo[l], bo_l,  nullptr, nullptr, 0.f, 1.0f, nullptr, a2, 0, 256, 0};
            gp.s[1] = {A3, 256, WM3[l], bm3_l, degf,    nullptr, 0.f, 1.0f, nullptr, a3, 0, 256, 0};
            gemm_bz<<<dim3(4, 64, 2), 256, 0, stream>>>(gp, ct);
        }

        // h = LN(h + a1 + a2 + a3)
        ln_kernel<<<N_NODES, 256, 0, stream>>>(h, h16, a1, a2, a3, lng_l, lnb_l);
    }

    colpool<<<H_F, 256, 0, stream>>>(h, pooled);
    classifier<<<1, 256, 0, stream>>>(pooled, Wc1, bc1, Wc2, bc2, (float*)d_out);
}

// Round 15
// 613.527 us; speedup vs baseline: 1.0711x; 1.0711x over previous
//
#include <hip/hip_runtime.h>
#include <hip/hip_bf16.h>

#define N_NODES 4096
#define E_EDGES 65536
#define IN_F    512
#define H_F     256
#define QD      256
#define NHEAD   8
#define HD      32
#define OUT_F   10
#define L_LAYERS 2
#define CT_N    50

enum { FLAG_RELU = 1, FLAG_ACCUM = 2, FLAG_WF32 = 4, FLAG_WB16 = 8 };

typedef __attribute__((ext_vector_type(8))) __bf16 bf16x8;
typedef __attribute__((ext_vector_type(4))) float f32x4;

union PU { bf16x8 v; __hip_bfloat16 h[8]; __hip_bfloat162 b2[4]; };

// ---------------------------------------------------------------------------
// bf16 MFMA GEMM.  A: bf16 [M][K] row-major (lda).  B: bf16 [N][K] (B^T layout).
// EDGE mode: A-row i built on the fly: relu(Z[tgtp[i]][k] + Z[srcp[i]][256+k] + kbias[k])
// ---------------------------------------------------------------------------
template<int BM, int BN, bool EDGE>
__global__ __launch_bounds__(256) void gemm_mfma(
    const __hip_bfloat16* __restrict__ A, int lda,
    const __hip_bfloat16* __restrict__ B, int ldb,
    float* __restrict__ Cf, __hip_bfloat16* __restrict__ Cb, int ldc,
    int K,
    const float* __restrict__ bias, const float* __restrict__ rowscale,
    const int* __restrict__ tgtp, const int* __restrict__ srcp,
    const float* __restrict__ kbias,
    int flags)
{
    constexpr int WM = BM / 2, WN = BN / 2, MT = WM / 16, NT = WN / 16;
    constexpr int LDT = 40;   // 80B row stride -> max 2-way bank alias (free, m136)
    __shared__ alignas(16) __hip_bfloat16 As[BM * LDT];
    __shared__ alignas(16) __hip_bfloat16 Bs[BN * LDT];

    const int tid = threadIdx.x;
    const int w = tid >> 6, lane = tid & 63, l16 = lane & 15, quad = lane >> 4;
    const int wm = w >> 1, wn = w & 1;
    const int bm = blockIdx.y * BM, bn = blockIdx.x * BN;

    f32x4 acc[MT][NT];
    #pragma unroll
    for (int i = 0; i < MT; ++i)
        #pragma unroll
        for (int j = 0; j < NT; ++j)
            #pragma unroll
            for (int r = 0; r < 4; ++r) acc[i][j][r] = 0.f;

    for (int k0 = 0; k0 < K; k0 += 32) {
        #pragma unroll
        for (int f = tid; f < BM * 4; f += 256) {
            int r = f >> 2, sg = f & 3;
            if (EDGE) {
                int i = bm + r;
                int tg = tgtp[i], sr = srcp[i];
                PU z1, z2, o;
                z1.v = *reinterpret_cast<const bf16x8*>(A + (size_t)tg * 512 + k0 + sg * 8);
                z2.v = *reinterpret_cast<const bf16x8*>(A + (size_t)sr * 512 + 256 + k0 + sg * 8);
                float4 b0 = *reinterpret_cast<const float4*>(kbias + k0 + sg * 8);
                float4 b1 = *reinterpret_cast<const float4*>(kbias + k0 + sg * 8 + 4);
                float bb[8] = {b0.x, b0.y, b0.z, b0.w, b1.x, b1.y, b1.z, b1.w};
                #pragma unroll
                for (int j = 0; j < 8; ++j) {
                    float v = __bfloat162float(z1.h[j]) + __bfloat162float(z2.h[j]) + bb[j];
                    o.h[j] = __float2bfloat16(fmaxf(v, 0.f));
                }
                *reinterpret_cast<bf16x8*>(&As[r * LDT + sg * 8]) = o.v;
            } else {
                *reinterpret_cast<uint4*>(&As[r * LDT + sg * 8]) =
                    *reinterpret_cast<const uint4*>(A + (size_t)(bm + r) * lda + k0 + sg * 8);
            }
        }
        #pragma unroll
        for (int f = tid; f < BN * 4; f += 256) {
            int r = f >> 2, sg = f & 3;
            *reinterpret_cast<uint4*>(&Bs[r * LDT + sg * 8]) =
                *reinterpret_cast<const uint4*>(B + (size_t)(bn + r) * ldb + k0 + sg * 8);
        }
        __syncthreads();
        bf16x8 af[MT], bfr[NT];
        #pragma unroll
        for (int mt = 0; mt < MT; ++mt)
            af[mt] = *reinterpret_cast<const bf16x8*>(&As[(wm * WM + mt * 16 + l16) * LDT + quad * 8]);
        #pragma unroll
        for (int nt = 0; nt < NT; ++nt)
            bfr[nt] = *reinterpret_cast<const bf16x8*>(&Bs[(wn * WN + nt * 16 + l16) * LDT + quad * 8]);
        #pragma unroll
        for (int mt = 0; mt < MT; ++mt)
            #pragma unroll
            for (int nt = 0; nt < NT; ++nt)
                acc[mt][nt] = __builtin_amdgcn_mfma_f32_16x16x32_bf16(af[mt], bfr[nt], acc[mt][nt], 0, 0, 0);
        __syncthreads();
    }

    #pragma unroll
    for (int mt = 0; mt < MT; ++mt) {
        #pragma unroll
        for (int nt = 0; nt < NT; ++nt) {
            int col = bn + wn * WN + nt * 16 + l16;
            #pragma unroll
            for (int r = 0; r < 4; ++r) {
                int row = bm + wm * WM + mt * 16 + quad * 4 + r;
                float v = acc[mt][nt][r];
                if (bias) {
                    float bv = bias[col];
                    if (rowscale) bv *= rowscale[row];
                    v += bv;
                }
                if (flags & FLAG_RELU) v = fmaxf(v, 0.f);
                size_t off = (size_t)row * ldc + col;
                if (flags & FLAG_ACCUM)     Cf[off] += v;
                else if (flags & FLAG_WF32) Cf[off] = v;
                if (flags & FLAG_WB16)      Cb[off] = __float2bfloat16(v);
            }
        }
    }
}

// ---------------------------------------------------------------------------
// Batched (grid.z) 64x64 GEMM slices: M=4096, N=256 (per slice), K=256, ldb=256.
// Output: vtout -> transposed bf16 Vt[col*4096+row]; Cf -> fp32; else bf16.
// ---------------------------------------------------------------------------
struct GSet { const __hip_bfloat16* A; int lda; const __hip_bfloat16* B;
              const float* bias; const float* rowscale;
              const float* extra; float esc; float cscale;
              __hip_bfloat16* C; float* Cf; int vtout; int ldc; int coloff; };
struct GPack { GSet s[8]; };

__global__ __launch_bounds__(256) void gemm_bz(GPack p, const int* __restrict__ eidx)
{
    GSet g = p.s[blockIdx.z];
    constexpr int LDT = 40;
    __shared__ alignas(16) __hip_bfloat16 As[64 * LDT];
    __shared__ alignas(16) __hip_bfloat16 Bs[64 * LDT];

    const int tid = threadIdx.x;
    const int w = tid >> 6, lane = tid & 63, l16 = lane & 15, quad = lane >> 4;
    const int wm = w >> 1, wn = w & 1;
    const int bm = blockIdx.y * 64, bn = blockIdx.x * 64;

    f32x4 acc[2][2];
    #pragma unroll
    for (int i = 0; i < 2; ++i)
        #pragma unroll
        for (int j = 0; j < 2; ++j)
            #pragma unroll
            for (int r = 0; r < 4; ++r) acc[i][j][r] = 0.f;

    for (int k0 = 0; k0 < 256; k0 += 32) {
        #pragma unroll
        for (int f = tid; f < 256; f += 256) {
            int r = f >> 2, sg = f & 3;
            *reinterpret_cast<uint4*>(&As[r * LDT + sg * 8]) =
                *reinterpret_cast<const uint4*>(g.A + (size_t)(bm + r) * g.lda + k0 + sg * 8);
            *reinterpret_cast<uint4*>(&Bs[r * LDT + sg * 8]) =
                *reinterpret_cast<const uint4*>(g.B + (size_t)(bn + r) * 256 + k0 + sg * 8);
        }
        __syncthreads();
        bf16x8 af[2], bfr[2];
        #pragma unroll
        for (int mt = 0; mt < 2; ++mt)
            af[mt] = *reinterpret_cast<const bf16x8*>(&As[(wm * 32 + mt * 16 + l16) * LDT + quad * 8]);
        #pragma unroll
        for (int nt = 0; nt < 2; ++nt)
            bfr[nt] = *reinterpret_cast<const bf16x8*>(&Bs[(wn * 32 + nt * 16 + l16) * LDT + quad * 8]);
        #pragma unroll
        for (int mt = 0; mt < 2; ++mt)
            #pragma unroll
            for (int nt = 0; nt < 2; ++nt)
                acc[mt][nt] = __builtin_amdgcn_mfma_f32_16x16x32_bf16(af[mt], bfr[nt], acc[mt][nt], 0, 0, 0);
        __syncthreads();
    }

    #pragma unroll
    for (int mt = 0; mt < 2; ++mt) {
        #pragma unroll
        for (int nt = 0; nt < 2; ++nt) {
            int colL = bn + wn * 32 + nt * 16 + l16;
            #pragma unroll
            for (int r = 0; r < 4; ++r) {
                int row = bm + wm * 32 + mt * 16 + quad * 4 + r;
                float v = acc[mt][nt][r];
                if (g.bias) {
                    float bv = g.bias[colL];
                    if (g.rowscale) bv *= g.rowscale[row];
                    v += bv;
                }
                if (g.extra) v += g.esc * g.extra[(size_t)eidx[row] * QD + colL];
                v *= g.cscale;
                if (g.vtout)
                    g.C[(size_t)colL * 4096 + row] = __float2bfloat16(v);
                else if (g.Cf)
                    g.Cf[(size_t)row * g.ldc + g.coloff + colL] = v;
                else
                    g.C[(size_t)row * g.ldc + g.coloff + colL] = __float2bfloat16(v);
            }
        }
    }
}

// ---------------------------------------------------------------------------
// fp32 tiled composite-weight GEMM (startup): 32x32 tile, BK=16, 2x2 microtile.
// ---------------------------------------------------------------------------
struct FDesc { const float* A; int lda; const float* B; int ldb; int tb;
               const float* bias; float* C; int M, N, K; };
struct FPack { FDesc d[16]; };

__global__ __launch_bounds__(256) void fgemm2(FPack p)
{
    FDesc c = p.d[blockIdx.z];
    int bm = blockIdx.y * 32, bn = blockIdx.x * 32;
    if (bm >= c.M || bn >= c.N) return;
    __shared__ float As[16][33];
    __shared__ float Bs[16][33];
    int tid = threadIdx.x;
    int tr = tid / 16, tc = tid % 16;
    float acc[2][2] = {};

    for (int k0 = 0; k0 < c.K; k0 += 16) {
        #pragma unroll
        for (int u = 0; u < 2; ++u) {
            int i = tid * 2 + u;
            int m = i >> 4, kk = i & 15;
            int row = bm + m, kg = k0 + kk;
            As[kk][m] = (row < c.M && kg < c.K) ? c.A[(size_t)row * c.lda + kg] : 0.f;
        }
        if (c.tb) {
            #pragma unroll
            for (int u = 0; u < 2; ++u) {
                int i = tid * 2 + u;
                int n = i >> 4, kk = i & 15;
                int col = bn + n, kg = k0 + kk;
                Bs[kk][n] = (col < c.N && kg < c.K) ? c.B[(size_t)col * c.ldb + kg] : 0.f;
            }
        } else {
            #pragma unroll
            for (int u = 0; u < 2; ++u) {
                int i = tid * 2 + u;
                int kk = i >> 5, n = i & 31;
                int col = bn + n, kg = k0 + kk;
                Bs[kk][n] = (col < c.N && kg < c.K) ? c.B[(size_t)kg * c.ldb + col] : 0.f;
            }
        }
        __syncthreads();
        #pragma unroll
        for (int kk = 0; kk < 16; ++kk) {
            float a0 = As[kk][tr * 2], a1 = As[kk][tr * 2 + 1];
            float b0 = Bs[kk][tc * 2], b1 = Bs[kk][tc * 2 + 1];
            acc[0][0] = fmaf(a0, b0, acc[0][0]);
            acc[0][1] = fmaf(a0, b1, acc[0][1]);
            acc[1][0] = fmaf(a1, b0, acc[1][0]);
            acc[1][1] = fmaf(a1, b1, acc[1][1]);
        }
        __syncthreads();
    }

    #pragma unroll
    for (int i = 0; i < 2; ++i) {
        int row = bm + tr * 2 + i;
        if (row >= c.M) continue;
        #pragma unroll
        for (int j = 0; j < 2; ++j) {
            int col = bn + tc * 2 + j;
            if (col >= c.N) continue;
            float v = acc[i][j];
            if (c.bias) v += c.bias[col];
            c.C[(size_t)row * c.N + col] = v;
        }
    }
}

// ---------------------------------------------------------------------------
// Flash MHA v9: max-free exp2 softmax, 32 q-rows shared by 8 waves (512-thr
// blocks, 8-way key split), additive merge.  grid (128, 8).
// ---------------------------------------------------------------------------
__global__ __launch_bounds__(512) void mha_flash9(
    const __hip_bfloat16* __restrict__ Qm,
    const __hip_bfloat16* __restrict__ Km,
    const __hip_bfloat16* __restrict__ Vt, __hip_bfloat16* __restrict__ Out)
{
    const int hh = blockIdx.y;
    const int tid = threadIdx.x;
    const int w = tid >> 6, lane = tid & 63, l16 = lane & 15, quad = lane >> 4;
    const int qb = blockIdx.x * 32;

    __shared__ float Osh[7][2][64][8];
    __shared__ float Lsh[7][2][16];

    const bf16x8 aq0 = *reinterpret_cast<const bf16x8*>(
        Qm + (size_t)(qb + l16) * 256 + hh * 32 + quad * 8);
    const bf16x8 aq1 = *reinterpret_cast<const bf16x8*>(
        Qm + (size_t)(qb + 16 + l16) * 256 + hh * 32 + quad * 8);
    const __hip_bfloat16* vb0 = Vt + (size_t)(hh * 32 + l16) * 4096;
    const __hip_bfloat16* vb1 = vb0 + (size_t)16 * 4096;
    const int rowoff = (l16 >> 2) * 8 + (l16 & 3);
    const f32x4 zero = {0.f, 0.f, 0.f, 0.f};

    f32x4 o00 = zero, o01 = zero, o10 = zero, o11 = zero;
    float l0 = 0.f, l1 = 0.f;

    const int kstart = w * 512;
    for (int kt = 0; kt < 8; ++kt) {
        const int kbase = kstart + kt * 64;
        bf16x8 kf[4];
        #pragma unroll
        for (int c = 0; c < 2; ++c)
            #pragma unroll
            for (int st = 0; st < 2; ++st)
                kf[c * 2 + st] = *reinterpret_cast<const bf16x8*>(
                    Km + (size_t)(kbase + c * 32 + st * 4 + rowoff) * 256 + hh * 32 + quad * 8);
        bf16x8 v00 = *reinterpret_cast<const bf16x8*>(vb0 + kbase + quad * 8);
        bf16x8 v01 = *reinterpret_cast<const bf16x8*>(vb1 + kbase + quad * 8);
        bf16x8 v10 = *reinterpret_cast<const bf16x8*>(vb0 + kbase + 32 + quad * 8);
        bf16x8 v11 = *reinterpret_cast<const bf16x8*>(vb1 + kbase + 32 + quad * 8);

        // ---- set 0 ----
        {
            f32x4 s[4];
            #pragma unroll
            for (int i = 0; i < 4; ++i)
                s[i] = __builtin_amdgcn_mfma_f32_16x16x32_bf16(kf[i], aq0, zero, 0, 0, 0);
            PU p0, p1;
            float ls = 0.f;
            #pragma unroll
            for (int i = 0; i < 4; ++i) {
                float e0 = exp2f(s[i][0]), e1 = exp2f(s[i][1]);
                float e2 = exp2f(s[i][2]), e3 = exp2f(s[i][3]);
                ls += (e0 + e1) + (e2 + e3);
                PU& pp = (i < 2) ? p0 : p1;
                pp.b2[(i & 1) * 2 + 0] = __float22bfloat162_rn(make_float2(e0, e1));
                pp.b2[(i & 1) * 2 + 1] = __float22bfloat162_rn(make_float2(e2, e3));
            }
            l0 += ls;
            o00 = __builtin_amdgcn_mfma_f32_16x16x32_bf16(v00, p0.v, o00, 0, 0, 0);
            o01 = __builtin_amdgcn_mfma_f32_16x16x32_bf16(v01, p0.v, o01, 0, 0, 0);
            o00 = __builtin_amdgcn_mfma_f32_16x16x32_bf16(v10, p1.v, o00, 0, 0, 0);
            o01 = __builtin_amdgcn_mfma_f32_16x16x32_bf16(v11, p1.v, o01, 0, 0, 0);
        }
        // ---- set 1 ----
        {
            f32x4 s[4];
            #pragma unroll
            for (int i = 0; i < 4; ++i)
                s[i] = __builtin_amdgcn_mfma_f32_16x16x32_bf16(kf[i], aq1, zero, 0, 0, 0);
            PU p0, p1;
            float ls = 0.f;
            #pragma unroll
            for (int i = 0; i < 4; ++i) {
                float e0 = exp2f(s[i][0]), e1 = exp2f(s[i][1]);
                float e2 = exp2f(s[i][2]), e3 = exp2f(s[i][3]);
                ls += (e0 + e1) + (e2 + e3);
                PU& pp = (i < 2) ? p0 : p1;
                pp.b2[(i & 1) * 2 + 0] = __float22bfloat162_rn(make_float2(e0, e1));
                pp.b2[(i & 1) * 2 + 1] = __float22bfloat162_rn(make_float2(e2, e3));
            }
            l1 += ls;
            o10 = __builtin_amdgcn_mfma_f32_16x16x32_bf16(v00, p0.v, o10, 0, 0, 0);
            o11 = __builtin_amdgcn_mfma_f32_16x16x32_bf16(v01, p0.v, o11, 0, 0, 0);
            o10 = __builtin_amdgcn_mfma_f32_16x16x32_bf16(v10, p1.v, o10, 0, 0, 0);
            o11 = __builtin_amdgcn_mfma_f32_16x16x32_bf16(v11, p1.v, o11, 0, 0, 0);
        }
    }

    l0 += __shfl_xor(l0, 16); l0 += __shfl_xor(l0, 32);
    l1 += __shfl_xor(l1, 16); l1 += __shfl_xor(l1, 32);

    if (w > 0) {
        #pragma unroll
        for (int r = 0; r < 4; ++r) {
            Osh[w - 1][0][lane][r]     = o00[r];
            Osh[w - 1][0][lane][4 + r] = o01[r];
            Osh[w - 1][1][lane][r]     = o10[r];
            Osh[w - 1][1][lane][4 + r] = o11[r];
        }
        if (quad == 0) { Lsh[w - 1][0][l16] = l0; Lsh[w - 1][1][l16] = l1; }
    }
    __syncthreads();
    if (w == 0) {
        #pragma unroll
        for (int ww = 0; ww < 7; ++ww) {
            #pragma unroll
            for (int r = 0; r < 4; ++r) {
                o00[r] += Osh[ww][0][lane][r];
                o01[r] += Osh[ww][0][lane][4 + r];
                o10[r] += Osh[ww][1][lane][r];
                o11[r] += Osh[ww][1][lane][4 + r];
            }
            l0 += Lsh[ww][0][l16];
            l1 += Lsh[ww][1][l16];
        }
        {
            float inv = 1.f / l0;
            __hip_bfloat16* dst = Out + (size_t)(qb + l16) * 256 + hh * 32;
            #pragma unroll
            for (int r = 0; r < 4; ++r) {
                dst[quad * 4 + r]      = __float2bfloat16(o00[r] * inv);
                dst[16 + quad * 4 + r] = __float2bfloat16(o01[r] * inv);
            }
        }
        {
            float inv = 1.f / l1;
            __hip_bfloat16* dst = Out + (size_t)(qb + 16 + l16) * 256 + hh * 32;
            #pragma unroll
            for (int r = 0; r < 4; ++r) {
                dst[quad * 4 + r]      = __float2bfloat16(o10[r] * inv);
                dst[16 + quad * 4 + r] = __float2bfloat16(o11[r] * inv);
            }
        }
    }
}

// build mask bitfield + per-target degree count in one pass
__global__ __launch_bounds__(256) void build_mask(const int* __restrict__ src,
                                                  const int* __restrict__ tgt,
                                                  unsigned* __restrict__ mb,
                                                  int* __restrict__ cnt)
{
    int e = blockIdx.x * 256 + threadIdx.x;
    if (e >= E_EDGES) return;
    int t = tgt[e];
    atomicOr(mb + (size_t)src[e] * (N_NODES / 32) + (t >> 5), 1u << (t & 31));
    atomicAdd(&cnt[t], 1);
}

__global__ __launch_bounds__(1024) void csr_scan(const int* __restrict__ cnt, int* __restrict__ off,
                                                 int* __restrict__ cursor, float* __restrict__ degf)
{
    __shared__ int sh[1024];
    int t = threadIdx.x;
    int base = t * 4;
    int c0 = cnt[base], c1 = cnt[base + 1], c2 = cnt[base + 2], c3 = cnt[base + 3];
    int sum = c0 + c1 + c2 + c3;
    sh[t] = sum; __syncthreads();
    for (int d = 1; d < 1024; d <<= 1) {
        int v = (t >= d) ? sh[t - d] : 0;
        __syncthreads();
        sh[t] += v;
        __syncthreads();
    }
    int excl = sh[t] - sum;
    int o0 = excl, o1 = excl + c0, o2 = o1 + c1, o3 = o2 + c2;
    off[base] = o0; off[base + 1] = o1; off[base + 2] = o2; off[base + 3] = o3;
    cursor[base] = o0; cursor[base + 1] = o1; cursor[base + 2] = o2; cursor[base + 3] = o3;
    degf[base] = (float)c0; degf[base + 1] = (float)c1;
    degf[base + 2] = (float)c2; degf[base + 3] = (float)c3;
    if (t == 1023) off[4096] = sh[t];
}

__global__ __launch_bounds__(256) void csr_fill(const int* __restrict__ src, const int* __restrict__ tgt,
                                                int* __restrict__ cursor,
                                                int* __restrict__ srcp, int* __restrict__ tgtp)
{
    int e = blockIdx.x * 256 + threadIdx.x;
    if (e >= E_EDGES) return;
    int t = tgt[e];
    int pos = atomicAdd(&cursor[t], 1);
    srcp[pos] = src[e];
    tgtp[pos] = t;
}

__global__ __launch_bounds__(256) void seg_sum(const int* __restrict__ off,
                                               const __hip_bfloat16* __restrict__ M2,
                                               __hip_bfloat16* __restrict__ A3)
{
    int n = blockIdx.x, t = threadIdx.x;
    int b0 = off[n], b1 = off[n + 1];
    float s = 0.f;
    for (int i = b0; i < b1; ++i)
        s += __bfloat162float(M2[(size_t)i * 256 + t]);
    A3[(size_t)n * 256 + t] = __float2bfloat16(s);
}

// Sparse graph-masked attention over bf16 Q,K,V. Writes out (=).
__global__ __launch_bounds__(256) void sparse_attn(
    const __hip_bfloat16* __restrict__ Q, const __hip_bfloat16* __restrict__ K,
    const __hip_bfloat16* __restrict__ V, int vld,
    const unsigned* __restrict__ maskb, float* __restrict__ outb)
{
    int i = blockIdx.x, t = threadIdx.x;
    __shared__ float qsh[256];
    __shared__ int   nb[1024];
    __shared__ float sc[1024];
    __shared__ int   cnt;
    __shared__ float red[4];
    __shared__ float smax, ssum;
    if (t == 0) cnt = 0;
    qsh[t] = __bfloat162float(Q[(size_t)i * 256 + t]);
    __syncthreads();
    if (t < 128) {
        unsigned wv = maskb[(size_t)i * 128 + t];
        while (wv) {
            int b = __ffs(wv) - 1; wv &= wv - 1;
            int p = atomicAdd(&cnt, 1);
            nb[p] = t * 32 + b;
        }
    }
    __syncthreads();
    int deg = cnt;
    int wid = t >> 6, lane = t & 63;
    if (deg > 0) {
        for (int n = wid; n < deg; n += 4) {
            union { uint2 u; __hip_bfloat16 h[4]; } kv;
            kv.u = *reinterpret_cast<const uint2*>(K + (size_t)nb[n] * 256 + lane * 4);
            float s = qsh[lane*4+0] * __bfloat162float(kv.h[0]) + qsh[lane*4+1] * __bfloat162float(kv.h[1])
                    + qsh[lane*4+2] * __bfloat162float(kv.h[2]) + qsh[lane*4+3] * __bfloat162float(kv.h[3]);
            #pragma unroll
            for (int off = 32; off; off >>= 1) s += __shfl_xor(s, off);
            if (lane == 0) sc[n] = s * 0.0625f;
        }
        __syncthreads();
        float m = -3.4e38f;
        for (int n = t; n < deg; n += 256) m = fmaxf(m, sc[n]);
        #pragma unroll
        for (int off = 32; off; off >>= 1) m = fmaxf(m, __shfl_xor(m, off));
        if (lane == 0) red[wid] = m;
        __syncthreads();
        if (t == 0) smax = fmaxf(fmaxf(red[0], red[1]), fmaxf(red[2], red[3]));
        __syncthreads();
        float ls = 0.f;
        for (int n = t; n < deg; n += 256) { float e = __expf(sc[n] - smax); sc[n] = e; ls += e; }
        #pragma unroll
        for (int off = 32; off; off >>= 1) ls += __shfl_xor(ls, off);
        if (lane == 0) red[wid] = ls;
        __syncthreads();
        if (t == 0) ssum = red[0] + red[1] + red[2] + red[3];
        __syncthreads();
        float inv = 1.f / ssum;
        float o = 0.f;
        for (int n = 0; n < deg; ++n)
            o += sc[n] * __bfloat162float(V[(size_t)nb[n] * vld + t]);
        outb[(size_t)i * 256 + t] = o * inv;
    } else {
        float o = 0.f;
        for (int j = 0; j < N_NODES; ++j) o += __bfloat162float(V[(size_t)j * vld + t]);
        outb[(size_t)i * 256 + t] = o * (1.f / N_NODES);
    }
}

// h = LN(h + a1 + a2 + a3)
__global__ __launch_bounds__(256) void ln_kernel(float* __restrict__ h, __hip_bfloat16* __restrict__ h16,
                                                 const float* __restrict__ a1,
                                                 const float* __restrict__ a2,
                                                 const float* __restrict__ a3,
                                                 const float* __restrict__ g, const float* __restrict__ b)
{
    int row = blockIdx.x, t = threadIdx.x;
    __shared__ float red[256];
    size_t off = ((size_t)row << 8) + t;
    float v = h[off] + a1[off] + a2[off] + a3[off];
    red[t] = v; __syncthreads();
    for (int s = 128; s > 0; s >>= 1) { if (t < s) red[t] += red[t + s]; __syncthreads(); }
    float mu = red[0] * (1.f / 256.f); __syncthreads();
    float d = v - mu;
    red[t] = d * d; __syncthreads();
    for (int s = 128; s > 0; s >>= 1) { if (t < s) red[t] += red[t + s]; __syncthreads(); }
    float var = red[0] * (1.f / 256.f);
    float r = d * rsqrtf(var + 1e-5f) * g[t] + b[t];
    h[off] = r;
    h16[off] = __float2bfloat16(r);
}

__global__ __launch_bounds__(256) void colpool(const float* __restrict__ h, float* __restrict__ p)
{
    int c = blockIdx.x, t = threadIdx.x;
    __shared__ float rs[256], rm[256];
    float s = 0.f, m = -3.4e38f;
    for (int row = t; row < N_NODES; row += 256) {
        float v = h[((size_t)row << 8) + c];
        s += v; m = fmaxf(m, v);
    }
    rs[t] = s; rm[t] = m; __syncthreads();
    for (int st = 128; st > 0; st >>= 1) {
        if (t < st) { rs[t] += rs[t + st]; rm[t] = fmaxf(rm[t], rm[t + st]); }
        __syncthreads();
    }
    if (t == 0) { p[c] = rs[0] * (1.f / N_NODES); p[256 + c] = rm[0]; }
}

__global__ __launch_bounds__(256) void classifier(const float* __restrict__ pooled,
                                                  const float* __restrict__ Wc1, const float* __restrict__ bc1,
                                                  const float* __restrict__ Wc2, const float* __restrict__ bc2,
                                                  float* __restrict__ out)
{
    __shared__ float p[512];
    __shared__ float z[256];
    int t = threadIdx.x;
    p[t] = pooled[t]; p[256 + t] = pooled[256 + t];
    __syncthreads();
    float s = bc1[t];
    for (int k = 0; k < 512; ++k) s = fmaf(p[k], Wc1[k * 256 + t], s);
    z[t] = fmaxf(s, 0.f);
    __syncthreads();
    if (t < OUT_F) {
        float o = bc2[t];
        for (int j = 0; j < 256; ++j) o = fmaf(z[j], Wc2[j * OUT_F + t], o);
        out[t] = o;
    }
}

// ---- bf16 conversion ----
struct CDesc { const float* s; __hip_bfloat16* d; int total; };
struct CPack { CDesc d[2]; };
__global__ __launch_bounds__(256) void convert_copy(CPack p)
{
    CDesc c = p.d[blockIdx.y];
    for (int i = blockIdx.x * 256 + threadIdx.x; i < c.total; i += gridDim.x * 256)
        c.d[i] = __float2bfloat16(c.s[i]);
}
// LDS-tiled transpose-convert: d[n*K+k] = bf16(s[k*sld+n]); coalesced both sides
struct TDesc { const float* s; __hip_bfloat16* d; int K, N, sld; };
struct TPack { TDesc d[23]; };
__global__ __launch_bounds__(256) void convert_t32(TPack p)
{
    TDesc c = p.d[blockIdx.z];
    int k0 = blockIdx.x * 32, n0 = blockIdx.y * 32;
    if (k0 >= c.K || n0 >= c.N) return;
    __shared__ float t[32][33];
    int tr = threadIdx.x >> 5, tc = threadIdx.x & 31;
    #pragma unroll
    for (int rr = 0; rr < 32; rr += 8)
        t[tc][tr + rr] = c.s[(size_t)(k0 + tr + rr) * c.sld + n0 + tc];
    __syncthreads();
    #pragma unroll
    for (int rr = 0; rr < 32; rr += 8)
        c.d[(size_t)(n0 + tr + rr) * c.K + k0 + tc] = __float2bfloat16(t[tr + rr][tc]);
}

extern "C" void kernel_launch(void* const* d_in, const int* in_sizes, int n_in,
                              void* d_out, int out_size, void* d_ws, size_t ws_size,
                              hipStream_t stream)
{
    const float* x    = (const float*)d_in[0];
    const int*   ei   = (const int*)d_in[1];
    const int*   ct   = (const int*)d_in[2];
    const float* Wi   = (const float*)d_in[3];
    const float* bi   = (const float*)d_in[4];
    const float* Wq   = (const float*)d_in[5];
    const float* bq   = (const float*)d_in[6];
    const float* Wk   = (const float*)d_in[7];
    const float* bk   = (const float*)d_in[8];
    const float* Wv   = (const float*)d_in[9];
    const float* bv   = (const float*)d_in[10];
    const float* Bc   = (const float*)d_in[11];
    const float* cemb = (const float*)d_in[12];
    const float* Win  = (const float*)d_in[13];
    const float* binp = (const float*)d_in[14];
    const float* Wo   = (const float*)d_in[15];
    const float* bo   = (const float*)d_in[16];
    const float* Wm1  = (const float*)d_in[17];
    const float* bm1  = (const float*)d_in[18];
    const float* Wm2  = (const float*)d_in[19];
    const float* bm2  = (const float*)d_in[20];
    const float* Wm3  = (const float*)d_in[21];
    const float* bm3  = (const float*)d_in[22];
    const float* lng  = (const float*)d_in[23];
    const float* lnb  = (const float*)d_in[24];
    const float* Wc1  = (const float*)d_in[25];
    const float* bc1  = (const float*)d_in[26];
    const float* Wc2  = (const float*)d_in[27];
    const float* bc2  = (const float*)d_in[28];

    const int* src = ei;
    const int* tgt = ei + E_EDGES;

    // ---- workspace carve-up ----
    char* wp = (char*)d_ws;
    auto alloc = [&](size_t bytes) { char* r = wp; wp += (bytes + 255) & ~(size_t)255; return r; };
    const size_t NH = (size_t)N_NODES * 256;
    float* h      = (float*)alloc(NH * 4);
    float* a1     = (float*)alloc(NH * 4);
    float* a2     = (float*)alloc(NH * 4);
    float* a3     = (float*)alloc(NH * 4);
    float* pooled = (float*)alloc(512 * 4);
    float* degf   = (float*)alloc(N_NODES * 4);
    __hip_bfloat16* x16 = (__hip_bfloat16*)alloc((size_t)N_NODES * 512 * 2);
    __hip_bfloat16* h16 = (__hip_bfloat16*)alloc(NH * 2);
    __hip_bfloat16* Qb  = (__hip_bfloat16*)alloc(NH * 2);
    __hip_bfloat16* Kb  = (__hip_bfloat16*)alloc(NH * 2);
    __hip_bfloat16* Vb  = (__hip_bfloat16*)alloc(NH * 2);
    __hip_bfloat16* Tq  = (__hip_bfloat16*)alloc(NH * 2);
    __hip_bfloat16* Tk  = (__hip_bfloat16*)alloc(NH * 2);
    __hip_bfloat16* Vt  = (__hip_bfloat16*)alloc(NH * 2);
    __hip_bfloat16* Z12 = (__hip_bfloat16*)alloc((size_t)N_NODES * 512 * 2);
    __hip_bfloat16* M216= (__hip_bfloat16*)alloc((size_t)E_EDGES * 256 * 2);
    __hip_bfloat16* A3  = (__hip_bfloat16*)alloc(NH * 2);
    __hip_bfloat16* Wi_t= (__hip_bfloat16*)alloc((size_t)256 * 512 * 2);
    // fp32 composite weights / biases / ce-tables, per layer
    float *Wqc_f[2], *Wkc_f[2], *Wqm_f[2], *Wkm_f[2], *Wvm_f[2];
    float *bqc[2], *bkc[2], *bqm[2], *bkm[2], *bvm[2], *ceq2[2], *cek2[2];
    for (int l = 0; l < 2; ++l) {
        Wqc_f[l] = (float*)alloc(65536 * 4); Wkc_f[l] = (float*)alloc(65536 * 4);
        Wqm_f[l] = (float*)alloc(65536 * 4); Wkm_f[l] = (float*)alloc(65536 * 4);
        Wvm_f[l] = (float*)alloc(65536 * 4);
        bqc[l] = (float*)alloc(256 * 4); bkc[l] = (float*)alloc(256 * 4);
        bqm[l] = (float*)alloc(256 * 4); bkm[l] = (float*)alloc(256 * 4);
        bvm[l] = (float*)alloc(256 * 4);
        ceq2[l] = (float*)alloc(CT_N * 256 * 4); cek2[l] = (float*)alloc(CT_N * 256 * 4);
    }
    // bf16 [N][K] weights: per layer: Wqc,Wkc,Wqm,Wkm,Wvm,Wv,Wo,Wm1a,Wm1b,Wm2,Wm3
    __hip_bfloat16* WB[2][11];
    for (int l = 0; l < 2; ++l)
        for (int m = 0; m < 11; ++m)
            WB[l][m] = (__hip_bfloat16*)alloc(65536 * 2);
    unsigned* maskb = (unsigned*)alloc((size_t)N_NODES * 128 * 4);
    int* cnt    = (int*)alloc(N_NODES * 4);
    int* cursor = (int*)alloc(N_NODES * 4);
    int* off    = (int*)alloc((N_NODES + 1) * 4);
    int* srcp   = (int*)alloc(E_EDGES * 4);
    int* tgtp   = (int*)alloc(E_EDGES * 4);

    // ---- startup: x conversion ----
    CPack cp; cp.d[0] = {x, x16, N_NODES * 512};
    convert_copy<<<dim3(256, 1), 256, 0, stream>>>(cp);

    // ---- composite fp32 weights (tiled fgemm2, 2 dependent waves) ----
    FPack f1; int n1 = 0;
    FPack f2; int n2 = 0;
    for (int l = 0; l < 2; ++l) {
        const float* Wq_l  = Wq + (size_t)l * 65536;
        const float* Wk_l  = Wk + (size_t)l * 65536;
        const float* Wv_l  = Wv + (size_t)l * 65536;
        const float* Bc_l  = Bc + (size_t)l * 65536;
        const float* Win_l = Win + (size_t)l * 256 * 768;
        const float* ce_l  = cemb + (size_t)l * CT_N * QD;
        const float* bq_l  = bq + l * 256;
        const float* bk_l  = bk + l * 256;
        const float* bv_l  = bv + l * 256;
        const float* bin_l = binp + l * 768;
        f1.d[n1++] = {Wq_l, 256, Bc_l, 256, 0, nullptr, Wqc_f[l], 256, 256, 256};
        f1.d[n1++] = {Wk_l, 256, Bc_l, 256, 1, nullptr, Wkc_f[l], 256, 256, 256};
        f1.d[n1++] = {bq_l, 256, Bc_l, 256, 0, nullptr, bqc[l], 1, 256, 256};
        f1.d[n1++] = {bk_l, 256, Bc_l, 256, 1, nullptr, bkc[l], 1, 256, 256};
        f2.d[n2++] = {Wqc_f[l], 256, Win_l,       768, 0, nullptr, Wqm_f[l], 256, 256, 256};
        f2.d[n2++] = {Wkc_f[l], 256, Win_l + 256, 768, 0, nullptr, Wkm_f[l], 256, 256, 256};
        f2.d[n2++] = {Wv_l,     256, Win_l + 512, 768, 0, nullptr, Wvm_f[l], 256, 256, 256};
        f2.d[n2++] = {ce_l,     256, Win_l,       768, 0, nullptr, ceq2[l], CT_N, 256, 256};
        f2.d[n2++] = {ce_l,     256, Win_l + 256, 768, 0, nullptr, cek2[l], CT_N, 256, 256};
        f2.d[n2++] = {bqc[l],   256, Win_l,       768, 0, bin_l,       bqm[l], 1, 256, 256};
        f2.d[n2++] = {bkc[l],   256, Win_l + 256, 768, 0, bin_l + 256, bkm[l], 1, 256, 256};
        f2.d[n2++] = {bv_l,     256, Win_l + 512, 768, 0, bin_l + 512, bvm[l], 1, 256, 256};
    }
    fgemm2<<<dim3(8, 8, n1), 256, 0, stream>>>(f1);
    fgemm2<<<dim3(8, 8, n2), 256, 0, stream>>>(f2);

    // ---- transpose-convert all [K][N] fp32 weights to bf16 [N][K] ----
    TPack tp; int ndt = 0;
    auto addT = [&](const float* s, __hip_bfloat16* d, int K, int N, int sld) { tp.d[ndt++] = {s, d, K, N, sld}; };
    addT(Wi, Wi_t, 512, 256, 256);
    for (int l = 0; l < 2; ++l) {
        const float* Wv_l  = Wv + (size_t)l * 65536;
        const float* Wo_l  = Wo + (size_t)l * 65536;
        const float* Wm1_l = Wm1 + (size_t)l * (2 * H_F + QD) * QD;  // layer stride 768*256!
        const float* Wm2_l = Wm2 + (size_t)l * 65536;
        const float* Wm3_l = Wm3 + (size_t)l * 65536;
        addT(Wqc_f[l], WB[l][0], 256, 256, 256);
        addT(Wkc_f[l], WB[l][1], 256, 256, 256);
        addT(Wqm_f[l], WB[l][2], 256, 256, 256);
        addT(Wkm_f[l], WB[l][3], 256, 256, 256);
        addT(Wvm_f[l], WB[l][4], 256, 256, 256);
        addT(Wv_l,     WB[l][5], 256, 256, 256);
        addT(Wo_l,     WB[l][6], 256, 256, 256);
        addT(Wm1_l,             WB[l][7], 256, 256, 256);
        addT(Wm1_l + 256 * 256, WB[l][8], 256, 256, 256);
        addT(Wm2_l,    WB[l][9],  256, 256, 256);
        addT(Wm3_l,    WB[l][10], 256, 256, 256);
    }
    convert_t32<<<dim3(16, 8, ndt), 256, 0, stream>>>(tp);

    hipMemsetAsync(maskb, 0, (size_t)N_NODES * 128 * 4, stream);
    hipMemsetAsync(cnt, 0, N_NODES * 4, stream);
    build_mask<<<E_EDGES / 256, 256, 0, stream>>>(src, tgt, maskb, cnt);
    csr_scan<<<1, 1024, 0, stream>>>(cnt, off, cursor, degf);
    csr_fill<<<E_EDGES / 256, 256, 0, stream>>>(src, tgt, cursor, srcp, tgtp);

    // h = relu(x @ Wi + bi)
    gemm_mfma<64, 64, false><<<dim3(4, 64), 256, 0, stream>>>(
        x16, 512, Wi_t, 512, h, h16, 256, 512,
        bi, nullptr, nullptr, nullptr, nullptr, FLAG_RELU | FLAG_WF32 | FLAG_WB16);

    const float QSCALE = 0.25507693f;   // log2(e)/sqrt(32)

    for (int l = 0; l < L_LAYERS; ++l) {
        const float* ce_l  = cemb + (size_t)l * CT_N * QD;
        const float* bo_l  = bo + l * QD;
        const float* bm1_l = bm1 + l * QD;
        const float* bm2_l = bm2 + l * QD;
        const float* bm3_l = bm3 + l * H_F;
        const float* lng_l = lng + l * H_F;
        const float* lnb_l = lnb + l * H_F;
        const float* bv_l  = bv + l * 256;

        // ---- one z=8 projection launch from h ----
        {
            GPack gp;
            gp.s[0] = {h16, 256, WB[l][0], bqc[l], nullptr, ce_l,    0.1f, 1.0f,   Qb,  nullptr, 0, 256, 0};
            gp.s[1] = {h16, 256, WB[l][1], bkc[l], nullptr, ce_l,    0.1f, 1.0f,   Kb,  nullptr, 0, 256, 0};
            gp.s[2] = {h16, 256, WB[l][5], bv_l,   nullptr, nullptr, 0.f,  1.0f,   Vb,  nullptr, 0, 256, 0};
            gp.s[3] = {h16, 256, WB[l][2], bqm[l], nullptr, ceq2[l], 0.1f, QSCALE, Tq,  nullptr, 0, 256, 0};
            gp.s[4] = {h16, 256, WB[l][3], bkm[l], nullptr, cek2[l], 0.1f, 1.0f,   Tk,  nullptr, 0, 256, 0};
            gp.s[5] = {h16, 256, WB[l][4], bvm[l], nullptr, nullptr, 0.f,  1.0f,   Vt,  nullptr, 1, 256, 0};
            gp.s[6] = {h16, 256, WB[l][7], nullptr, nullptr, nullptr, 0.f, 1.0f,   Z12, nullptr, 0, 512, 0};
            gp.s[7] = {h16, 256, WB[l][8], nullptr, nullptr, nullptr, 0.f, 1.0f,   Z12, nullptr, 0, 512, 256};
            gemm_bz<<<dim3(4, 64, 8), 256, 0, stream>>>(gp, ct);
        }

        // sparse graph-masked attention -> a1
        sparse_attn<<<N_NODES, 256, 0, stream>>>(Qb, Kb, Vb, 256, maskb, a1);

        // flash MHA v9 (8-wave blocks): heads -> Qb
        mha_flash9<<<dim3(128, NHEAD), 512, 0, stream>>>(Tq, Tk, Vt, Qb);

        // edge MLP: fused-gather edge GEMM -> M216, seg-sum -> A3
        gemm_mfma<128, 128, true><<<dim3(2, E_EDGES / 128), 256, 0, stream>>>(
            Z12, 512, WB[l][9], 256, nullptr, M216, 256, 256,
            bm2_l, nullptr, tgtp, srcp, bm1_l, FLAG_RELU | FLAG_WB16);
        seg_sum<<<N_NODES, 256, 0, stream>>>(off, M216, A3);

        // batched fp32 outputs: a2 = heads@Wo + bo ; a3 = A3@Wm3 + deg*bm3
        {
            GPack gp;
            gp.s[0] = {Qb, 256, WB[l][6],  bo_l,  nullptr, nullptr, 0.f, 1.0f, nullptr, a2, 0, 256, 0};
            gp.s[1] = {A3, 256, WB[l][10], bm3_l, degf,    nullptr, 0.f, 1.0f, nullptr, a3, 0, 256, 0};
            gemm_bz<<<dim3(4, 64, 2), 256, 0, stream>>>(gp, ct);
        }

        // h = LN(h + a1 + a2 + a3)
        ln_kernel<<<N_NODES, 256, 0, stream>>>(h, h16, a1, a2, a3, lng_l, lnb_l);
    }

    colpool<<<H_F, 256, 0, stream>>>(h, pooled);
    classifier<<<1, 256, 0, stream>>>(pooled, Wc1, bc1, Wc2, bc2, (float*)d_out);
}